// Round 4
// baseline (662.550 us; speedup 1.0000x reference)
//
#include <hip/hip_runtime.h>
#include <hip/hip_bf16.h>
#include <math.h>

#define NPTS  8192
#define DIM   512
#define KNNK  15
#define NPAIR 105
#define CINF  3.0e38f

// knn tiling
#define NI      128
#define NJSPLIT 8
#define NJ      (NPTS/NJSPLIT)   // 1024
#define JS      128
#define NSUB    (NJ/JS)          // 8
#define BK      16               // k chunk (ushorts)
#define NCH     (DIM/BK)         // 32
#define DSTRIDE 130

// LDS map (bytes): 4 staging bufs (16KB each: A 8KB + B 8KB) alias sdist[128][130]
#define BUFSZ    16384
#define EXI_OFF  66560
#define SQJ_OFF  67072
#define TLS_OFF  71168
#define KNN_LDS  72192

typedef __attribute__((ext_vector_type(8))) short short8;
typedef __attribute__((ext_vector_type(4))) float f32x4;
typedef __attribute__((ext_vector_type(16))) float f32x16;

static __device__ __forceinline__ float wave_sum_f(float v) {
#pragma unroll
  for (int m = 32; m > 0; m >>= 1) v += __shfl_xor(v, m, 64);
  return v;
}

static __device__ __forceinline__ void load_lds16(const void* g, void* l) {
  __builtin_amdgcn_global_load_lds(
      (const __attribute__((address_space(1))) void*)g,
      (__attribute__((address_space(3))) void*)l, 16, 0, 0);
}

static __device__ __forceinline__ void bf16split(float x, short& h, short& l) {
  __hip_bfloat16 hb = __float2bfloat16(x);
  const float hf = __bfloat162float(hb);
  __hip_bfloat16 lb = __float2bfloat16(x - hf);
  h = *(short*)&hb;
  l = *(short*)&lb;
}

// ---------------------------------------------------------------- prep
__global__ __launch_bounds__(256) void prep_kernel(
    const float* __restrict__ E, float* __restrict__ sqn,
    ushort* __restrict__ Ehi, ushort* __restrict__ Elo) {
  const int row  = blockIdx.x * 4 + (threadIdx.x >> 6);
  const int lane = threadIdx.x & 63;
  float s = 0.f;
#pragma unroll
  for (int c = 0; c < 8; ++c) {
    const int d0 = lane + 64 * c;
    const float x = E[(size_t)row * DIM + d0];
    s = fmaf(x, x, s);
    short h, l;
    bf16split(x, h, l);
    Ehi[(size_t)row * DIM + d0] = (ushort)h;
    Elo[(size_t)row * DIM + d0] = (ushort)l;
  }
  s = wave_sum_f(s);
  if (lane == 0) sqn[row] = s;
}

// ---------------------------------------------------------------- knn
// 128x128 tile, 4 waves (64x64 each, 2x2 of 32x32x16 MFMA). Depth-3
// prefetch: 4 LDS bufs, s_waitcnt vmcnt(8) + raw s_barrier per chunk.
// LDS tile rows are 64B = [hi0 hi1 lo0 lo1] granules XOR-swizzled by
// m = d ^ ((row>>1)&3)  -> all b128 frag reads are bank-conflict-free.
__global__ __launch_bounds__(256, 2) void knn_kernel(
    const ushort* __restrict__ Ehi, const ushort* __restrict__ Elo,
    const float* __restrict__ sqn,
    float* __restrict__ cd, int* __restrict__ ci) {
  __shared__ __align__(16) char sm[KNN_LDS];
  float* sdist = (float*)sm;
  float* exi   = (float*)(sm + EXI_OFF);
  float* sqjs  = (float*)(sm + SQJ_OFF);
  float* tls   = (float*)(sm + TLS_OFF);

  const int tid = threadIdx.x;
  const int w   = tid >> 6;
  const int L   = tid & 63;
  const int wr  = w >> 1;
  const int wc  = w & 1;
  const int l31 = L & 31;
  const int kh  = L >> 5;            // k-half for frags
  const int s3  = (l31 >> 1) & 3;    // frag swizzle key
  const int jsplit = blockIdx.x;
  const int i0  = blockIdx.y * NI;
  const int j0  = jsplit * NJ;

  if (tid < 32) ((float4*)exi)[tid] = ((const float4*)(sqn + i0))[tid];
  ((float4*)sqjs)[tid] = ((const float4*)(sqn + j0))[tid];
  tls[tid] = CINF;

  // staging role: waves 0,1 -> A rows (i); waves 2,3 -> B rows (j)
  const int half = w & 1;
  const int d    = (L & 3) ^ ((L >> 3) & 3);   // data granule this lane fetches
  const ushort* srcSel = (d < 2) ? Ehi : Elo;
  const int kus = (d & 1) * 8;                 // ushort offset within chunk
  const int tileoff = ((w >> 1) ? 8192 : 0) + half * 4096;

  const int myrow = tid >> 1;
  const int h     = tid & 1;
  const int gi    = i0 + myrow;

  float td[15]; int tj[15];
#pragma unroll
  for (int p = 0; p < 15; ++p) { td[p] = CINF; tj[p] = -1; }

  __syncthreads();

  for (int js = 0; js < NSUB; ++js) {
    const int jrow0 = j0 + js * JS;
    const int trow0 = (w < 2) ? i0 : jrow0;
    // per-lane global staging base (row = trow0 + half*64 + L>>2)
    const ushort* gstage =
        srcSel + (size_t)(trow0 + half * 64 + (L >> 2)) * DIM + kus;

    f32x16 acc[2][2];
#pragma unroll
    for (int t = 0; t < 2; ++t)
#pragma unroll
      for (int u = 0; u < 2; ++u)
#pragma unroll
        for (int r = 0; r < 16; ++r) acc[t][u][r] = 0.f;

    // prologue: stage chunks 0,1,2
#pragma unroll
    for (int c = 0; c < 3; ++c) {
      char* lp = sm + (c & 3) * BUFSZ + tileoff;
      const ushort* gp = gstage + c * BK;
#pragma unroll
      for (int o = 0; o < 4; ++o)
        load_lds16(gp + (size_t)o * 16 * DIM, lp + o * 1024);
    }

#pragma unroll
    for (int ch = 0; ch < NCH; ++ch) {
      if (ch < NCH - 2)       { asm volatile("s_waitcnt vmcnt(8)" ::: "memory"); }
      else if (ch == NCH - 2) { asm volatile("s_waitcnt vmcnt(4)" ::: "memory"); }
      else                    { asm volatile("s_waitcnt vmcnt(0)" ::: "memory"); }
      __builtin_amdgcn_s_barrier();

      if (ch + 3 < NCH) {
        char* lp = sm + ((ch + 3) & 3) * BUFSZ + tileoff;
        const ushort* gp = gstage + (ch + 3) * BK;
#pragma unroll
        for (int o = 0; o < 4; ++o)
          load_lds16(gp + (size_t)o * 16 * DIM, lp + o * 1024);
      }

      const char* Ab = sm + (ch & 3) * BUFSZ;
      const char* Bb = Ab + 8192;
      short8 ah[2], al[2], bh[2], bl[2];
#pragma unroll
      for (int t = 0; t < 2; ++t) {
        const int Ra = wr * 64 + t * 32 + l31;
        ah[t] = *(const short8*)(Ab + Ra * 64 + (kh ^ s3) * 16);
        al[t] = *(const short8*)(Ab + Ra * 64 + (((kh | 2)) ^ s3) * 16);
        const int Rb = wc * 64 + t * 32 + l31;
        bh[t] = *(const short8*)(Bb + Rb * 64 + (kh ^ s3) * 16);
        bl[t] = *(const short8*)(Bb + Rb * 64 + (((kh | 2)) ^ s3) * 16);
      }
#pragma unroll
      for (int t = 0; t < 2; ++t)
#pragma unroll
        for (int u = 0; u < 2; ++u) {
          acc[t][u] = __builtin_amdgcn_mfma_f32_32x32x16_bf16(ah[t], bh[u], acc[t][u], 0, 0, 0);
          acc[t][u] = __builtin_amdgcn_mfma_f32_32x32x16_bf16(ah[t], bl[u], acc[t][u], 0, 0, 0);
          acc[t][u] = __builtin_amdgcn_mfma_f32_32x32x16_bf16(al[t], bh[u], acc[t][u], 0, 0, 0);
        }
    }
    __syncthreads();   // full drain; staging region reusable as sdist

    // ---- partial distances (sqj - 2*dot; exi added at merge; order-invariant)
#pragma unroll
    for (int t = 0; t < 2; ++t)
#pragma unroll
      for (int u = 0; u < 2; ++u) {
        const float sq = sqjs[js * 128 + wc * 64 + u * 32 + l31];
#pragma unroll
        for (int rg = 0; rg < 16; ++rg) {
          const int rowc  = (rg & 3) + 8 * (rg >> 2) + 4 * kh;
          const int row_l = wr * 64 + t * 32 + rowc;
          sdist[row_l * DSTRIDE + wc * 64 + u * 32 + l31] =
              sq - 2.0f * acc[t][u][rg];
        }
      }
    __syncthreads();

    // ---- tau + self-poke + scan
    const float tau = fminf(tls[myrow * 2], tls[myrow * 2 + 1]);
    const int selfc = gi - jrow0;
    if (selfc >= 0 && selfc < JS && (selfc & 1) == h)
      sdist[myrow * DSTRIDE + selfc] = CINF;

    const float* rp = sdist + myrow * DSTRIDE + h;
    float guard = fminf(tau, td[14]);
    const int jbase = jrow0 + h;
#pragma unroll 4
    for (int q = 0; q < 64; ++q) {
      const float dd = rp[2 * q];
      if (dd < guard) {
        float cdv = dd; int cjv = jbase + 2 * q;
#pragma unroll
        for (int p = 0; p < 15; ++p) {
          const bool lt = cdv < td[p];
          const float vmin = lt ? cdv : td[p];
          const float vmax = lt ? td[p] : cdv;
          const int imin = lt ? cjv : tj[p];
          const int imax = lt ? tj[p] : cjv;
          td[p] = vmin; tj[p] = imin; cdv = vmax; cjv = imax;
        }
        guard = fminf(tau, td[14]);
      }
    }
    tls[myrow * 2 + h] = td[14];
    __syncthreads();
  }

  // ---- pair-merge -> top-15 per (row, split), restore +exi, clamp
  float* md  = sdist;
  int*   mi_ = (int*)(sm + 16384);
#pragma unroll
  for (int p = 0; p < 15; ++p) {
    md[(myrow * 2 + h) * 15 + p]  = td[p];
    mi_[(myrow * 2 + h) * 15 + p] = tj[p];
  }
  __syncthreads();
  if (h == 0) {
    const float* da = &md[(myrow * 2 + 0) * 15];
    const float* db = &md[(myrow * 2 + 1) * 15];
    const int*   ia = &mi_[(myrow * 2 + 0) * 15];
    const int*   ib = &mi_[(myrow * 2 + 1) * 15];
    const float exr = exi[myrow];
    int pa = 0, pb = 0;
    const size_t base = ((size_t)gi * NJSPLIT + jsplit) * KNNK;
    for (int s2 = 0; s2 < KNNK; ++s2) {
      const float va = da[pa], vb = db[pb];
      float v; int ix;
      if (va <= vb) { v = va; ix = ia[pa]; ++pa; }
      else          { v = vb; ix = ib[pb]; ++pb; }
      cd[base + s2] = fmaxf(v + exr, 0.f);
      ci[base + s2] = ix;
    }
  }
}

// ---------------------------------------------------------------- merge
__global__ __launch_bounds__(256) void kmerge_kernel(
    const float* __restrict__ cd, const int* __restrict__ ci,
    float* __restrict__ kd, int* __restrict__ ki) {
  const int row = blockIdx.x * 4 + (threadIdx.x >> 6);
  const int L   = threadIdx.x & 63;
  const size_t base = (size_t)row * (NJSPLIT * KNNK);
  float v0 = (L < 120)      ? cd[base + L]      : CINF;
  float v1 = (L + 64 < 120) ? cd[base + L + 64] : CINF;
  int   i0v = (L < 120)      ? ci[base + L]      : -1;
  int   i1v = (L + 64 < 120) ? ci[base + L + 64] : -1;
  for (int sel = 0; sel < KNNK; ++sel) {
    float v; int idx, slot;
    if (v1 < v0) { v = v1; idx = i1v; slot = (L << 1) | 1; }
    else         { v = v0; idx = i0v; slot = (L << 1); }
#pragma unroll
    for (int off = 32; off > 0; off >>= 1) {
      const float ov = __shfl_down(v, off, 64);
      const int   oi = __shfl_down(idx, off, 64);
      const int   os = __shfl_down(slot, off, 64);
      if (ov < v) { v = ov; idx = oi; slot = os; }
    }
    const float vmin = __shfl(v, 0, 64);
    const int   imin = __shfl(idx, 0, 64);
    const int   smin = __shfl(slot, 0, 64);
    if (L == (smin >> 1)) { if (smin & 1) v1 = CINF; else v0 = CINF; }
    if (L == 0) {
      kd[row * KNNK + sel] = sqrtf(fmaxf(vmin, 1e-12f));
      ki[row * KNNK + sel] = imin;
    }
  }
}

// ---------------------------------------------------------------- sig
// One wave per point, zero block barriers. Raw-difference gram via
// split-bf16 MFMA; norms from the gram diagonal; shuffle bitonic-128.
__global__ __launch_bounds__(256) void sig_kernel(
    const float* __restrict__ E, const float* __restrict__ kd,
    const int* __restrict__ ki, const float* __restrict__ refc,
    const float* __restrict__ refa, double* __restrict__ acc) {
  __shared__ float gsm[4][292];   // per-wave: gram 16x17 (=272) + inv[16]

  const int tid = threadIdx.x;
  const int wid = tid >> 6;
  const int L   = tid & 63;
  const int i   = blockIdx.x * 4 + wid;

  // curvature
  float curvs;
  {
    float dd = (L < KNNK) ? kd[i * KNNK + L] : 0.f;
    float tot = wave_sum_f(dd);
    float mean_d = tot / (float)KNNK + 1e-8f;
    float diff = (L < KNNK) ? (dd / mean_d - refc[i * KNNK + L]) : 0.f;
    curvs = wave_sum_f(diff * diff);
  }

  // gram of raw neighbor differences (row = L&15; row 15 -> self => zero)
  const int myr = L & 15;
  const int nb  = (myr < KNNK) ? ki[i * KNNK + myr] : i;
  const float4* nb4 = (const float4*)(E + (size_t)nb * DIM);
  const float4* ei4 = (const float4*)(E + (size_t)i * DIM);
  const int qo = (L >> 4) * 2;   // float4 index of this lane's 8-elem k-slice

  f32x4 gH, gX;
#pragma unroll
  for (int r = 0; r < 4; ++r) { gH[r] = 0.f; gX[r] = 0.f; }

#pragma unroll
  for (int c = 0; c < 16; ++c) {
    const float4 f0 = nb4[qo + c * 8];
    const float4 f1 = nb4[qo + 1 + c * 8];
    const float4 e0 = ei4[qo + c * 8];
    const float4 e1 = ei4[qo + 1 + c * 8];
    float v[8];
    v[0] = f0.x - e0.x; v[1] = f0.y - e0.y; v[2] = f0.z - e0.z; v[3] = f0.w - e0.w;
    v[4] = f1.x - e1.x; v[5] = f1.y - e1.y; v[6] = f1.z - e1.z; v[7] = f1.w - e1.w;
    short8 ah, al;
#pragma unroll
    for (int q = 0; q < 8; ++q) {
      short hh, ll;
      bf16split(v[q], hh, ll);
      ah[q] = hh; al[q] = ll;
    }
    gH = __builtin_amdgcn_mfma_f32_16x16x32_bf16(ah, ah, gH, 0, 0, 0);
    gX = __builtin_amdgcn_mfma_f32_16x16x32_bf16(ah, al, gX, 0, 0, 0);
    gX = __builtin_amdgcn_mfma_f32_16x16x32_bf16(al, ah, gX, 0, 0, 0);
  }

  // write gram to per-wave LDS: C/D layout col=L&15, row=(L>>4)*4+q
#pragma unroll
  for (int q = 0; q < 4; ++q)
    gsm[wid][((L >> 4) * 4 + q) * 17 + (L & 15)] = gH[q] + gX[q];
  asm volatile("s_waitcnt lgkmcnt(0)" ::: "memory");

  if (L < 16) {
    const float dv = gsm[wid][L * 17 + L];
    const float nrm = sqrtf(fmaxf(dv, 0.f));
    gsm[wid][272 + L] = 1.0f / fmaxf(nrm, 1e-8f);
  }
  asm volatile("s_waitcnt lgkmcnt(0)" ::: "memory");

  // cosines for pairs p = L and p+64
  float v0 = CINF, v1 = CINF;
#pragma unroll
  for (int s = 0; s < 2; ++s) {
    const int p = L + 64 * s;
    if (p < NPAIR) {
      int a = 0, rem = p, cnt = 14;
      while (rem >= cnt) { rem -= cnt; --cnt; ++a; }
      const int b = a + 1 + rem;
      const float cv = gsm[wid][a * 17 + b] * gsm[wid][272 + a] * gsm[wid][272 + b];
      if (s == 0) v0 = cv; else v1 = cv;
    }
  }

  // shuffle bitonic sort of 128 elems (e = 2L + slot), ascending
#pragma unroll
  for (int k = 2; k <= 128; k <<= 1) {
#pragma unroll
    for (int j = k >> 1; j >= 1; j >>= 1) {
      const bool dir = ((L & (k >> 1)) == 0);
      if (j == 1) {
        const float lo = fminf(v0, v1), hi = fmaxf(v0, v1);
        v0 = dir ? lo : hi;
        v1 = dir ? hi : lo;
      } else {
        const int m = j >> 1;
        const float o0 = __shfl_xor(v0, m, 64);
        const float o1 = __shfl_xor(v1, m, 64);
        const bool lower = ((L & m) == 0);
        v0 = (lower == dir) ? fminf(v0, o0) : fmaxf(v0, o0);
        v1 = (lower == dir) ? fminf(v1, o1) : fmaxf(v1, o1);
      }
    }
  }

  // angular loss vs sorted reference (rank 2L, 2L+1)
  float part = 0.f;
  {
    const int r0 = 2 * L, r1 = 2 * L + 1;
    if (r0 < NPAIR) { const float dd = v0 - refa[(size_t)i * NPAIR + r0]; part += dd * dd; }
    if (r1 < NPAIR) { const float dd = v1 - refa[(size_t)i * NPAIR + r1]; part += dd * dd; }
  }
  part = wave_sum_f(part);
  if (L == 0) {
    atomicAdd(&acc[0], (double)curvs);
    atomicAdd(&acc[1], (double)part);
  }
}

// ---------------------------------------------------------------- fin
__global__ void fin_kernel(const double* __restrict__ acc,
                           float* __restrict__ out) {
  if (threadIdx.x == 0 && blockIdx.x == 0) {
    const double curv = acc[0] / ((double)NPTS * (double)KNNK);
    const double ang  = acc[1] / ((double)NPTS * (double)NPAIR);
    out[0] = (float)(0.3 * curv + 0.7 * ang);
  }
}

// ---------------------------------------------------------------- launch
extern "C" void kernel_launch(void* const* d_in, const int* in_sizes, int n_in,
                              void* d_out, int out_size, void* d_ws,
                              size_t ws_size, hipStream_t stream) {
  const float* E    = (const float*)d_in[0];
  const float* refc = (const float*)d_in[1];
  const float* refa = (const float*)d_in[2];
  float* out = (float*)d_out;

  char* ws = (char*)d_ws;
  double* acc = (double*)ws;
  float*  sqn = (float*)(ws + 1024);
  float*  kd  = (float*)(ws + 33792);
  int*    ki  = (int*)(ws + 525312);
  ushort* Ehi = (ushort*)(ws + 1048576);
  ushort* Elo = (ushort*)(ws + 9437184);
  float*  cd  = (float*)(ws + 17825792);
  int*    ci  = (int*)(ws + 21757952);

  hipMemsetAsync(ws, 0, 16, stream);
  prep_kernel<<<NPTS / 4, 256, 0, stream>>>(E, sqn, Ehi, Elo);
  knn_kernel<<<dim3(NJSPLIT, NPTS / NI), 256, 0, stream>>>(Ehi, Elo, sqn, cd, ci);
  kmerge_kernel<<<NPTS / 4, 256, 0, stream>>>(cd, ci, kd, ki);
  sig_kernel<<<NPTS / 4, 256, 0, stream>>>(E, kd, ki, refc, refa, acc);
  fin_kernel<<<1, 64, 0, stream>>>(acc, out);
}

// Round 5
// 619.065 us; speedup vs baseline: 1.0702x; 1.0702x over previous
//
#include <hip/hip_runtime.h>
#include <hip/hip_bf16.h>
#include <math.h>

#define NPTS  8192
#define DIM   512
#define KNNK  15
#define NPAIR 105
#define CINF  3.0e38f

// knn tiling
#define NI      128
#define NJSPLIT 8
#define NJ      (NPTS/NJSPLIT)   // 1024
#define JS      128
#define NSUB    (NJ/JS)          // 8
#define BK      32
#define NCH     (DIM/BK)         // 16
#define DSTRIDE 130

// knn LDS byte map: sdist[128][130] aliases the two 32KB staging buffers
#define BUF0_OFF   0
#define BUF1_OFF   33280
#define EXI_OFF    66560
#define SQJ_OFF    67072
#define TLS_OFF    71168
#define KNN_LDS    72192

typedef __attribute__((ext_vector_type(8))) short short8;
typedef __attribute__((ext_vector_type(4))) float f32x4;

static __device__ __forceinline__ float wave_sum_f(float v) {
#pragma unroll
  for (int m = 32; m > 0; m >>= 1) v += __shfl_xor(v, m, 64);
  return v;
}

static __device__ __forceinline__ void load_lds16(const void* g, void* l) {
  __builtin_amdgcn_global_load_lds(
      (const __attribute__((address_space(1))) void*)g,
      (__attribute__((address_space(3))) void*)l, 16, 0, 0);
}

static __device__ __forceinline__ void bf16split(float x, short& h, short& l) {
  __hip_bfloat16 hb = __float2bfloat16(x);
  const float hf = __bfloat162float(hb);
  __hip_bfloat16 lb = __float2bfloat16(x - hf);
  h = *(short*)&hb;
  l = *(short*)&lb;
}

// ---------------------------------------------------------------- prep
__global__ __launch_bounds__(256) void prep_kernel(
    const float* __restrict__ E, float* __restrict__ sqn,
    ushort* __restrict__ Ehi, ushort* __restrict__ Elo) {
  const int row  = blockIdx.x * 4 + (threadIdx.x >> 6);
  const int lane = threadIdx.x & 63;
  float s = 0.f;
#pragma unroll
  for (int c = 0; c < 8; ++c) {
    const int d0 = lane + 64 * c;
    const float x = E[(size_t)row * DIM + d0];
    s = fmaf(x, x, s);
    short h, l;
    bf16split(x, h, l);
    Ehi[(size_t)row * DIM + d0] = (ushort)h;
    Elo[(size_t)row * DIM + d0] = (ushort)l;
  }
  s = wave_sum_f(s);
  if (lane == 0) sqn[row] = s;
}

// ---------------------------------------------------------------- knn
// grid (64, 8): blockIdx.x = i-tile  -> XCD = x%8, so each XCD carries only
// 8 distinct A-sets (2 MB, L2-resident; the 8x per-subtile A re-stage hits
// L2). blockIdx.y = jsplit; the 8 same-jsplit blocks per XCD stream B
// subtiles in loose lockstep (transient L2 sharing).
// K-loop: R3 structure (BK=32, 16x16x32 MFMA, double-buffered
// global_load_lds, 1 barrier per chunk).
__global__ __launch_bounds__(256, 2) void knn_kernel(
    const ushort* __restrict__ Ehi, const ushort* __restrict__ Elo,
    const float* __restrict__ sqn,
    float* __restrict__ cd, int* __restrict__ ci) {
  __shared__ __align__(16) char sm[KNN_LDS];
  float* sdist = (float*)sm;
  float* exi   = (float*)(sm + EXI_OFF);
  float* sqjs  = (float*)(sm + SQJ_OFF);
  float* tls   = (float*)(sm + TLS_OFF);

  const int tid = threadIdx.x;
  const int w   = tid >> 6;
  const int L   = tid & 63;
  const int wr  = w >> 1;
  const int wc  = w & 1;
  const int i0  = blockIdx.x * NI;     // i-tile (XCD-affine)
  const int jsplit = blockIdx.y;
  const int j0  = jsplit * NJ;

  if (tid < 32) ((float4*)exi)[tid] = ((const float4*)(sqn + i0))[tid];
  ((float4*)sqjs)[tid] = ((const float4*)(sqn + j0))[tid];
  tls[tid] = CINF;

  const ushort* srcBase = (w & 1) ? Elo : Ehi;   // tiles: 0=Ahi 1=Alo 2=Bhi 3=Blo
  const int lrow = L >> 2;
  const int lk8  = (L & 3) * 8;

  const int myrow = tid >> 1;
  const int h     = tid & 1;
  const int gi    = i0 + myrow;

  float td[15]; int tj[15];
#pragma unroll
  for (int p = 0; p < 15; ++p) { td[p] = CINF; tj[p] = -1; }

  __syncthreads();

  for (int js = 0; js < NSUB; ++js) {
    const int jrow0 = j0 + js * JS;
    const int trow0 = (w < 2) ? i0 : jrow0;
    const ushort* gbase = srcBase + (size_t)(trow0 + lrow) * DIM + lk8;

    f32x4 acc[4][4];
#pragma unroll
    for (int fr = 0; fr < 4; ++fr)
#pragma unroll
      for (int fc = 0; fc < 4; ++fc)
#pragma unroll
        for (int r = 0; r < 4; ++r) acc[fr][fc][r] = 0.f;

    // prologue: stage chunk 0 into buf0
    {
      char* lp = sm + BUF0_OFF + w * 8192;
#pragma unroll
      for (int s = 0; s < 8; ++s)
        load_lds16(gbase + (size_t)s * 16 * DIM, lp + s * 1024);
    }
    __syncthreads();

#pragma unroll 2
    for (int ch = 0; ch < NCH; ++ch) {
      const int cb = (ch & 1) ? BUF1_OFF : BUF0_OFF;
      const int nbo = (ch & 1) ? BUF0_OFF : BUF1_OFF;
      if (ch < NCH - 1) {
        char* lp = sm + nbo + w * 8192;
        const ushort* gp = gbase + (ch + 1) * BK;
#pragma unroll
        for (int s = 0; s < 8; ++s)
          load_lds16(gp + (size_t)s * 16 * DIM, lp + s * 1024);
      }

      const ushort* sAhi = (const ushort*)(sm + cb);
      const ushort* sAlo = (const ushort*)(sm + cb + 8192);
      const ushort* sBhi = (const ushort*)(sm + cb + 16384);
      const ushort* sBlo = (const ushort*)(sm + cb + 24576);

      short8 ah[4], al[4], bh[4], bl[4];
      const int q16 = (L >> 4) * 8;
#pragma unroll
      for (int f = 0; f < 4; ++f) {
        const int ra = f * 16 + (L & 15);
        ah[f] = *(const short8*)&sAhi[(wr * 64 + ra) * BK + q16];
        al[f] = *(const short8*)&sAlo[(wr * 64 + ra) * BK + q16];
        bh[f] = *(const short8*)&sBhi[(wc * 64 + ra) * BK + q16];
        bl[f] = *(const short8*)&sBlo[(wc * 64 + ra) * BK + q16];
      }
#pragma unroll
      for (int fr = 0; fr < 4; ++fr)
#pragma unroll
        for (int fc = 0; fc < 4; ++fc) {
          acc[fr][fc] = __builtin_amdgcn_mfma_f32_16x16x32_bf16(ah[fr], bh[fc], acc[fr][fc], 0, 0, 0);
          acc[fr][fc] = __builtin_amdgcn_mfma_f32_16x16x32_bf16(ah[fr], bl[fc], acc[fr][fc], 0, 0, 0);
          acc[fr][fc] = __builtin_amdgcn_mfma_f32_16x16x32_bf16(al[fr], bh[fc], acc[fr][fc], 0, 0, 0);
        }
      __syncthreads();   // drains next-chunk staging; orders buffer reuse
    }

    // ---- partial distances (sqj - 2*dot; exi added at merge)
    float sqjv[4];
#pragma unroll
    for (int fc = 0; fc < 4; ++fc)
      sqjv[fc] = sqjs[js * 128 + wc * 64 + fc * 16 + (L & 15)];
#pragma unroll
    for (int fr = 0; fr < 4; ++fr)
#pragma unroll
      for (int fc = 0; fc < 4; ++fc)
#pragma unroll
        for (int r = 0; r < 4; ++r) {
          const int row_l = wr * 64 + fr * 16 + (L >> 4) * 4 + r;
          const int col_l = wc * 64 + fc * 16 + (L & 15);
          sdist[row_l * DSTRIDE + col_l] = sqjv[fc] - 2.0f * acc[fr][fc][r];
        }
    __syncthreads();

    // ---- tau + self-poke + scan
    const float tau = fminf(tls[myrow * 2], tls[myrow * 2 + 1]);
    const int selfc = gi - jrow0;
    if (selfc >= 0 && selfc < JS && (selfc & 1) == h)
      sdist[myrow * DSTRIDE + selfc] = CINF;

    const float* rp = sdist + myrow * DSTRIDE + h;
    float guard = fminf(tau, td[14]);
    const int jbase = jrow0 + h;
#pragma unroll 4
    for (int q = 0; q < 64; ++q) {
      const float dd = rp[2 * q];
      if (dd < guard) {
        float cdv = dd; int cjv = jbase + 2 * q;
#pragma unroll
        for (int p = 0; p < 15; ++p) {
          const bool lt = cdv < td[p];
          const float vmin = lt ? cdv : td[p];
          const float vmax = lt ? td[p] : cdv;
          const int imin = lt ? cjv : tj[p];
          const int imax = lt ? tj[p] : cjv;
          td[p] = vmin; tj[p] = imin; cdv = vmax; cjv = imax;
        }
        guard = fminf(tau, td[14]);
      }
    }
    tls[myrow * 2 + h] = td[14];
    __syncthreads();
  }

  // ---- pair-merge -> top-15 per (row, split); restore +exi, clamp
  float* md  = sdist;
  int*   mi_ = (int*)(sm + 16384);
#pragma unroll
  for (int p = 0; p < 15; ++p) {
    md[(myrow * 2 + h) * 15 + p]  = td[p];
    mi_[(myrow * 2 + h) * 15 + p] = tj[p];
  }
  __syncthreads();
  if (h == 0) {
    const float* da = &md[(myrow * 2 + 0) * 15];
    const float* db = &md[(myrow * 2 + 1) * 15];
    const int*   ia = &mi_[(myrow * 2 + 0) * 15];
    const int*   ib = &mi_[(myrow * 2 + 1) * 15];
    const float exr = exi[myrow];
    int pa = 0, pb = 0;
    const size_t base = ((size_t)gi * NJSPLIT + jsplit) * KNNK;
    for (int s2 = 0; s2 < KNNK; ++s2) {
      const float va = da[pa], vb = db[pb];
      float v; int ix;
      if (va <= vb) { v = va; ix = ia[pa]; ++pa; }
      else          { v = vb; ix = ib[pb]; ++pb; }
      cd[base + s2] = fmaxf(v + exr, 0.f);
      ci[base + s2] = ix;
    }
  }
}

// ---------------------------------------------------------------- merge
__global__ __launch_bounds__(256) void kmerge_kernel(
    const float* __restrict__ cd, const int* __restrict__ ci,
    float* __restrict__ kd, int* __restrict__ ki) {
  const int row = blockIdx.x * 4 + (threadIdx.x >> 6);
  const int L   = threadIdx.x & 63;
  const size_t base = (size_t)row * (NJSPLIT * KNNK);
  float v0 = (L < 120)      ? cd[base + L]      : CINF;
  float v1 = (L + 64 < 120) ? cd[base + L + 64] : CINF;
  int   i0v = (L < 120)      ? ci[base + L]      : -1;
  int   i1v = (L + 64 < 120) ? ci[base + L + 64] : -1;
  for (int sel = 0; sel < KNNK; ++sel) {
    float v; int idx, slot;
    if (v1 < v0) { v = v1; idx = i1v; slot = (L << 1) | 1; }
    else         { v = v0; idx = i0v; slot = (L << 1); }
#pragma unroll
    for (int off = 32; off > 0; off >>= 1) {
      const float ov = __shfl_down(v, off, 64);
      const int   oi = __shfl_down(idx, off, 64);
      const int   os = __shfl_down(slot, off, 64);
      if (ov < v) { v = ov; idx = oi; slot = os; }
    }
    const float vmin = __shfl(v, 0, 64);
    const int   imin = __shfl(idx, 0, 64);
    const int   smin = __shfl(slot, 0, 64);
    if (L == (smin >> 1)) { if (smin & 1) v1 = CINF; else v0 = CINF; }
    if (L == 0) {
      kd[row * KNNK + sel] = sqrtf(fmaxf(vmin, 1e-12f));
      ki[row * KNNK + sel] = imin;
    }
  }
}

// ---------------------------------------------------------------- sig
// One wave per point. Raw-difference gram via split-bf16 MFMA; norms from
// the gram diagonal; shuffle bitonic-128; no block barriers.
__global__ __launch_bounds__(256) void sig_kernel(
    const float* __restrict__ E, const float* __restrict__ kd,
    const int* __restrict__ ki, const float* __restrict__ refc,
    const float* __restrict__ refa, double* __restrict__ acc) {
  __shared__ float gsm[4][292];   // per-wave: gram 16x17 (=272) + inv[16]

  const int tid = threadIdx.x;
  const int wid = tid >> 6;
  const int L   = tid & 63;
  const int i   = blockIdx.x * 4 + wid;

  // curvature
  float curvs;
  {
    float dd = (L < KNNK) ? kd[i * KNNK + L] : 0.f;
    float tot = wave_sum_f(dd);
    float mean_d = tot / (float)KNNK + 1e-8f;
    float diff = (L < KNNK) ? (dd / mean_d - refc[i * KNNK + L]) : 0.f;
    curvs = wave_sum_f(diff * diff);
  }

  // gram of raw neighbor differences (row = L&15; row 15 -> self => zero)
  const int myr = L & 15;
  const int nb  = (myr < KNNK) ? ki[i * KNNK + myr] : i;
  const float4* nb4 = (const float4*)(E + (size_t)nb * DIM);
  const float4* ei4 = (const float4*)(E + (size_t)i * DIM);
  const int qo = (L >> 4) * 2;   // float4 index of this lane's 8-elem k-slice

  f32x4 gH, gX;
#pragma unroll
  for (int r = 0; r < 4; ++r) { gH[r] = 0.f; gX[r] = 0.f; }

#pragma unroll
  for (int c = 0; c < 16; ++c) {
    const float4 f0 = nb4[qo + c * 8];
    const float4 f1 = nb4[qo + 1 + c * 8];
    const float4 e0 = ei4[qo + c * 8];
    const float4 e1 = ei4[qo + 1 + c * 8];
    float v[8];
    v[0] = f0.x - e0.x; v[1] = f0.y - e0.y; v[2] = f0.z - e0.z; v[3] = f0.w - e0.w;
    v[4] = f1.x - e1.x; v[5] = f1.y - e1.y; v[6] = f1.z - e1.z; v[7] = f1.w - e1.w;
    short8 ah, al;
#pragma unroll
    for (int q = 0; q < 8; ++q) {
      short hh, ll;
      bf16split(v[q], hh, ll);
      ah[q] = hh; al[q] = ll;
    }
    gH = __builtin_amdgcn_mfma_f32_16x16x32_bf16(ah, ah, gH, 0, 0, 0);
    gX = __builtin_amdgcn_mfma_f32_16x16x32_bf16(ah, al, gX, 0, 0, 0);
    gX = __builtin_amdgcn_mfma_f32_16x16x32_bf16(al, ah, gX, 0, 0, 0);
  }

  // write gram to per-wave LDS: C/D layout col=L&15, row=(L>>4)*4+q
#pragma unroll
  for (int q = 0; q < 4; ++q)
    gsm[wid][((L >> 4) * 4 + q) * 17 + (L & 15)] = gH[q] + gX[q];
  asm volatile("s_waitcnt lgkmcnt(0)" ::: "memory");

  if (L < 16) {
    const float dv = gsm[wid][L * 17 + L];
    const float nrm = sqrtf(fmaxf(dv, 0.f));
    gsm[wid][272 + L] = 1.0f / fmaxf(nrm, 1e-8f);
  }
  asm volatile("s_waitcnt lgkmcnt(0)" ::: "memory");

  // cosines for pairs p = L and p+64
  float v0 = CINF, v1 = CINF;
#pragma unroll
  for (int s = 0; s < 2; ++s) {
    const int p = L + 64 * s;
    if (p < NPAIR) {
      int a = 0, rem = p, cnt = 14;
      while (rem >= cnt) { rem -= cnt; --cnt; ++a; }
      const int b = a + 1 + rem;
      const float cv = gsm[wid][a * 17 + b] * gsm[wid][272 + a] * gsm[wid][272 + b];
      if (s == 0) v0 = cv; else v1 = cv;
    }
  }

  // shuffle bitonic sort of 128 elems (e = 2L + slot), ascending
#pragma unroll
  for (int k = 2; k <= 128; k <<= 1) {
#pragma unroll
    for (int j = k >> 1; j >= 1; j >>= 1) {
      const bool dir = ((L & (k >> 1)) == 0);
      if (j == 1) {
        const float lo = fminf(v0, v1), hi = fmaxf(v0, v1);
        v0 = dir ? lo : hi;
        v1 = dir ? hi : lo;
      } else {
        const int m = j >> 1;
        const float o0 = __shfl_xor(v0, m, 64);
        const float o1 = __shfl_xor(v1, m, 64);
        const bool lower = ((L & m) == 0);
        v0 = (lower == dir) ? fminf(v0, o0) : fmaxf(v0, o0);
        v1 = (lower == dir) ? fminf(v1, o1) : fmaxf(v1, o1);
      }
    }
  }

  // angular loss vs sorted reference (rank 2L, 2L+1)
  float part = 0.f;
  {
    const int r0 = 2 * L, r1 = 2 * L + 1;
    if (r0 < NPAIR) { const float dd = v0 - refa[(size_t)i * NPAIR + r0]; part += dd * dd; }
    if (r1 < NPAIR) { const float dd = v1 - refa[(size_t)i * NPAIR + r1]; part += dd * dd; }
  }
  part = wave_sum_f(part);
  if (L == 0) {
    atomicAdd(&acc[0], (double)curvs);
    atomicAdd(&acc[1], (double)part);
  }
}

// ---------------------------------------------------------------- fin
__global__ void fin_kernel(const double* __restrict__ acc,
                           float* __restrict__ out) {
  if (threadIdx.x == 0 && blockIdx.x == 0) {
    const double curv = acc[0] / ((double)NPTS * (double)KNNK);
    const double ang  = acc[1] / ((double)NPTS * (double)NPAIR);
    out[0] = (float)(0.3 * curv + 0.7 * ang);
  }
}

// ---------------------------------------------------------------- launch
extern "C" void kernel_launch(void* const* d_in, const int* in_sizes, int n_in,
                              void* d_out, int out_size, void* d_ws,
                              size_t ws_size, hipStream_t stream) {
  const float* E    = (const float*)d_in[0];
  const float* refc = (const float*)d_in[1];
  const float* refa = (const float*)d_in[2];
  float* out = (float*)d_out;

  char* ws = (char*)d_ws;
  double* acc = (double*)ws;
  float*  sqn = (float*)(ws + 1024);
  float*  kd  = (float*)(ws + 33792);
  int*    ki  = (int*)(ws + 525312);
  ushort* Ehi = (ushort*)(ws + 1048576);
  ushort* Elo = (ushort*)(ws + 9437184);
  float*  cd  = (float*)(ws + 17825792);
  int*    ci  = (int*)(ws + 21757952);

  hipMemsetAsync(ws, 0, 16, stream);
  prep_kernel<<<NPTS / 4, 256, 0, stream>>>(E, sqn, Ehi, Elo);
  knn_kernel<<<dim3(NPTS / NI, NJSPLIT), 256, 0, stream>>>(Ehi, Elo, sqn, cd, ci);
  kmerge_kernel<<<NPTS / 4, 256, 0, stream>>>(cd, ci, kd, ki);
  sig_kernel<<<NPTS / 4, 256, 0, stream>>>(E, kd, ki, refc, refa, acc);
  fin_kernel<<<1, 64, 0, stream>>>(acc, out);
}

// Round 6
// 572.191 us; speedup vs baseline: 1.1579x; 1.0819x over previous
//
#include <hip/hip_runtime.h>
#include <hip/hip_bf16.h>
#include <math.h>

#define NPTS  8192
#define DIM   512
#define KNNK  15
#define NPAIR 105
#define CINF  3.0e38f

// knn tiling
#define NI      128
#define NJSPLIT 8
#define NJ      (NPTS/NJSPLIT)   // 1024
#define JS      128
#define NSUB    (NJ/JS)          // 8
#define BK      32
#define NCH     (DIM/BK)         // 16
#define DSTRIDE 132              // 16B-aligned rows; writes conflict-free, b128 scan reads 2-way (free)

// knn LDS byte map: sdist[128][132] aliases the two 32KB staging buffers
#define BUF0_OFF   0
#define BUF1_OFF   33792
#define EXI_OFF    67584
#define SQJ_OFF    68096
#define TLS_OFF    72192
#define KNN_LDS    73216

typedef __attribute__((ext_vector_type(8))) short short8;
typedef __attribute__((ext_vector_type(4))) float f32x4;

static __device__ __forceinline__ float wave_sum_f(float v) {
#pragma unroll
  for (int m = 32; m > 0; m >>= 1) v += __shfl_xor(v, m, 64);
  return v;
}

static __device__ __forceinline__ void load_lds16(const void* g, void* l) {
  __builtin_amdgcn_global_load_lds(
      (const __attribute__((address_space(1))) void*)g,
      (__attribute__((address_space(3))) void*)l, 16, 0, 0);
}

static __device__ __forceinline__ void bf16split(float x, short& h, short& l) {
  __hip_bfloat16 hb = __float2bfloat16(x);
  const float hf = __bfloat162float(hb);
  __hip_bfloat16 lb = __float2bfloat16(x - hf);
  h = *(short*)&hb;
  l = *(short*)&lb;
}

// ---------------------------------------------------------------- prep
__global__ __launch_bounds__(256) void prep_kernel(
    const float* __restrict__ E, float* __restrict__ sqn,
    ushort* __restrict__ Ehi, ushort* __restrict__ Elo,
    double* __restrict__ acc) {
  if (blockIdx.x == 0 && threadIdx.x == 0) { acc[0] = 0.0; acc[1] = 0.0; }
  const int row  = blockIdx.x * 4 + (threadIdx.x >> 6);
  const int lane = threadIdx.x & 63;
  float s = 0.f;
#pragma unroll
  for (int c = 0; c < 8; ++c) {
    const int d0 = lane + 64 * c;
    const float x = E[(size_t)row * DIM + d0];
    s = fmaf(x, x, s);
    short h, l;
    bf16split(x, h, l);
    Ehi[(size_t)row * DIM + d0] = (ushort)h;
    Elo[(size_t)row * DIM + d0] = (ushort)l;
  }
  s = wave_sum_f(s);
  if (lane == 0) sqn[row] = s;
}

// ---------------------------------------------------------------- knn
// grid (64, 8): blockIdx.x = i-tile -> XCD = x%8 (A-set L2-resident).
// K-loop: BK=32, 16x16x32 MFMA, double-buffered global_load_lds.
// Scan: contiguous 64-col half-row per thread, float4 batches with
// min-of-4 guard pre-check.
__global__ __launch_bounds__(256, 2) void knn_kernel(
    const ushort* __restrict__ Ehi, const ushort* __restrict__ Elo,
    const float* __restrict__ sqn,
    float* __restrict__ cd, int* __restrict__ ci) {
  __shared__ __align__(16) char sm[KNN_LDS];
  float* sdist = (float*)sm;
  float* exi   = (float*)(sm + EXI_OFF);
  float* sqjs  = (float*)(sm + SQJ_OFF);
  float* tls   = (float*)(sm + TLS_OFF);

  const int tid = threadIdx.x;
  const int w   = tid >> 6;
  const int L   = tid & 63;
  const int wr  = w >> 1;
  const int wc  = w & 1;
  const int i0  = blockIdx.x * NI;     // i-tile (XCD-affine)
  const int jsplit = blockIdx.y;
  const int j0  = jsplit * NJ;

  if (tid < 32) ((float4*)exi)[tid] = ((const float4*)(sqn + i0))[tid];
  ((float4*)sqjs)[tid] = ((const float4*)(sqn + j0))[tid];
  tls[tid] = CINF;

  const ushort* srcBase = (w & 1) ? Elo : Ehi;   // tiles: 0=Ahi 1=Alo 2=Bhi 3=Blo
  const int lrow = L >> 2;
  const int lk8  = (L & 3) * 8;

  const int myrow = tid >> 1;
  const int h     = tid & 1;
  const int gi    = i0 + myrow;

  float td[15]; int tj[15];
#pragma unroll
  for (int p = 0; p < 15; ++p) { td[p] = CINF; tj[p] = -1; }

  __syncthreads();

  for (int js = 0; js < NSUB; ++js) {
    const int jrow0 = j0 + js * JS;
    const int trow0 = (w < 2) ? i0 : jrow0;
    const ushort* gbase = srcBase + (size_t)(trow0 + lrow) * DIM + lk8;

    f32x4 acc[4][4];
#pragma unroll
    for (int fr = 0; fr < 4; ++fr)
#pragma unroll
      for (int fc = 0; fc < 4; ++fc)
#pragma unroll
        for (int r = 0; r < 4; ++r) acc[fr][fc][r] = 0.f;

    // prologue: stage chunk 0 into buf0
    {
      char* lp = sm + BUF0_OFF + w * 8192;
#pragma unroll
      for (int s = 0; s < 8; ++s)
        load_lds16(gbase + (size_t)s * 16 * DIM, lp + s * 1024);
    }
    __syncthreads();

#pragma unroll 2
    for (int ch = 0; ch < NCH; ++ch) {
      const int cb = (ch & 1) ? BUF1_OFF : BUF0_OFF;
      const int nbo = (ch & 1) ? BUF0_OFF : BUF1_OFF;
      if (ch < NCH - 1) {
        char* lp = sm + nbo + w * 8192;
        const ushort* gp = gbase + (ch + 1) * BK;
#pragma unroll
        for (int s = 0; s < 8; ++s)
          load_lds16(gp + (size_t)s * 16 * DIM, lp + s * 1024);
      }

      const ushort* sAhi = (const ushort*)(sm + cb);
      const ushort* sAlo = (const ushort*)(sm + cb + 8192);
      const ushort* sBhi = (const ushort*)(sm + cb + 16384);
      const ushort* sBlo = (const ushort*)(sm + cb + 24576);

      short8 ah[4], al[4], bh[4], bl[4];
      const int q16 = (L >> 4) * 8;
#pragma unroll
      for (int f = 0; f < 4; ++f) {
        const int ra = f * 16 + (L & 15);
        ah[f] = *(const short8*)&sAhi[(wr * 64 + ra) * BK + q16];
        al[f] = *(const short8*)&sAlo[(wr * 64 + ra) * BK + q16];
        bh[f] = *(const short8*)&sBhi[(wc * 64 + ra) * BK + q16];
        bl[f] = *(const short8*)&sBlo[(wc * 64 + ra) * BK + q16];
      }
#pragma unroll
      for (int fr = 0; fr < 4; ++fr)
#pragma unroll
        for (int fc = 0; fc < 4; ++fc) {
          acc[fr][fc] = __builtin_amdgcn_mfma_f32_16x16x32_bf16(ah[fr], bh[fc], acc[fr][fc], 0, 0, 0);
          acc[fr][fc] = __builtin_amdgcn_mfma_f32_16x16x32_bf16(ah[fr], bl[fc], acc[fr][fc], 0, 0, 0);
          acc[fr][fc] = __builtin_amdgcn_mfma_f32_16x16x32_bf16(al[fr], bh[fc], acc[fr][fc], 0, 0, 0);
        }
      __syncthreads();   // drains next-chunk staging; orders buffer reuse
    }

    // ---- partial distances (sqj - 2*dot; exi added at merge)
    float sqjv[4];
#pragma unroll
    for (int fc = 0; fc < 4; ++fc)
      sqjv[fc] = sqjs[js * 128 + wc * 64 + fc * 16 + (L & 15)];
#pragma unroll
    for (int fr = 0; fr < 4; ++fr)
#pragma unroll
      for (int fc = 0; fc < 4; ++fc)
#pragma unroll
        for (int r = 0; r < 4; ++r) {
          const int row_l = wr * 64 + fr * 16 + (L >> 4) * 4 + r;
          const int col_l = wc * 64 + fc * 16 + (L & 15);
          sdist[row_l * DSTRIDE + col_l] = sqjv[fc] - 2.0f * acc[fr][fc][r];
        }
    __syncthreads();

    // ---- tau + self-poke + batch-4 scan over contiguous half-row
    const float tau = fminf(tls[myrow * 2], tls[myrow * 2 + 1]);
    const int selfc = gi - jrow0;
    if (selfc >= 0 && selfc < JS && h == (selfc >> 6))
      sdist[myrow * DSTRIDE + selfc] = CINF;

    const float* rp = sdist + myrow * DSTRIDE + 64 * h;
    float guard = fminf(tau, td[14]);
    const int jb = jrow0 + 64 * h;
#pragma unroll 2
    for (int q = 0; q < 16; ++q) {
      const float4 dv = *(const float4*)&rp[4 * q];
      const float mn = fminf(fminf(dv.x, dv.y), fminf(dv.z, dv.w));
      if (mn < guard) {
        const float c4[4] = {dv.x, dv.y, dv.z, dv.w};
#pragma unroll
        for (int t = 0; t < 4; ++t) {
          const float dd = c4[t];
          if (dd < guard) {
            float cdv = dd; int cjv = jb + 4 * q + t;
#pragma unroll
            for (int p = 0; p < 15; ++p) {
              const bool lt = cdv < td[p];
              const float vmin = lt ? cdv : td[p];
              const float vmax = lt ? td[p] : cdv;
              const int imin = lt ? cjv : tj[p];
              const int imax = lt ? tj[p] : cjv;
              td[p] = vmin; tj[p] = imin; cdv = vmax; cjv = imax;
            }
            guard = fminf(tau, td[14]);
          }
        }
      }
    }
    tls[myrow * 2 + h] = td[14];
    __syncthreads();
  }

  // ---- pair-merge -> top-15 per (row, split); restore +exi, clamp
  float* md  = sdist;
  int*   mi_ = (int*)(sm + 16384);
#pragma unroll
  for (int p = 0; p < 15; ++p) {
    md[(myrow * 2 + h) * 15 + p]  = td[p];
    mi_[(myrow * 2 + h) * 15 + p] = tj[p];
  }
  __syncthreads();
  if (h == 0) {
    const float* da = &md[(myrow * 2 + 0) * 15];
    const float* db = &md[(myrow * 2 + 1) * 15];
    const int*   ia = &mi_[(myrow * 2 + 0) * 15];
    const int*   ib = &mi_[(myrow * 2 + 1) * 15];
    const float exr = exi[myrow];
    int pa = 0, pb = 0;
    const size_t base = ((size_t)gi * NJSPLIT + jsplit) * KNNK;
    for (int s2 = 0; s2 < KNNK; ++s2) {
      const float va = da[pa], vb = db[pb];
      float v; int ix;
      if (va <= vb) { v = va; ix = ia[pa]; ++pa; }
      else          { v = vb; ix = ib[pb]; ++pb; }
      cd[base + s2] = fmaxf(v + exr, 0.f);
      ci[base + s2] = ix;
    }
  }
}

// ---------------------------------------------------------------- sig
// One wave per point. Fused: 8-way candidate merge (was kmerge) ->
// curvature -> raw-difference gram via split-bf16 MFMA (norms from the
// diagonal) -> shuffle bitonic-128 -> loss. No block barriers.
__global__ __launch_bounds__(256) void sig_kernel(
    const float* __restrict__ E, const float* __restrict__ cd,
    const int* __restrict__ ci, const float* __restrict__ refc,
    const float* __restrict__ refa, double* __restrict__ acc) {
  __shared__ float gsm[4][292];   // per-wave: gram 16x17 (=272) + inv[16]

  const int tid = threadIdx.x;
  const int wid = tid >> 6;
  const int L   = tid & 63;
  const int i   = blockIdx.x * 4 + wid;

  // ---- merge 8 sorted 15-lists -> top-15 (d, nb); lane-group captures row L&15
  const size_t mbase = (size_t)i * (NJSPLIT * KNNK);
  float v0 = (L < 120)      ? cd[mbase + L]      : CINF;
  float v1 = (L + 64 < 120) ? cd[mbase + L + 64] : CINF;
  int   j0v = (L < 120)      ? ci[mbase + L]      : -1;
  int   j1v = (L + 64 < 120) ? ci[mbase + L + 64] : -1;
  float myd = 0.f; int mynb = i;
  for (int sel = 0; sel < KNNK; ++sel) {
    float v; int idx, slot;
    if (v1 < v0) { v = v1; idx = j1v; slot = (L << 1) | 1; }
    else         { v = v0; idx = j0v; slot = (L << 1); }
#pragma unroll
    for (int off = 32; off > 0; off >>= 1) {
      const float ov = __shfl_down(v, off, 64);
      const int   oi = __shfl_down(idx, off, 64);
      const int   os = __shfl_down(slot, off, 64);
      if (ov < v) { v = ov; idx = oi; slot = os; }
    }
    const float vmin = __shfl(v, 0, 64);
    const int   imin = __shfl(idx, 0, 64);
    const int   smin = __shfl(slot, 0, 64);
    if ((L & 15) == sel) { myd = sqrtf(fmaxf(vmin, 1e-12f)); mynb = imin; }
    if (L == (smin >> 1)) { if (smin & 1) v1 = CINF; else v0 = CINF; }
  }

  // ---- curvature (lanes 0..14 hold d_0..d_14)
  float curvs;
  {
    float dd = (L < KNNK) ? myd : 0.f;
    float tot = wave_sum_f(dd);
    float mean_d = tot / (float)KNNK + 1e-8f;
    float diff = (L < KNNK) ? (dd / mean_d - refc[i * KNNK + L]) : 0.f;
    curvs = wave_sum_f(diff * diff);
  }

  // ---- gram of raw neighbor differences (row = L&15; row 15 = self -> zero)
  const float4* nb4 = (const float4*)(E + (size_t)mynb * DIM);
  const float4* ei4 = (const float4*)(E + (size_t)i * DIM);
  const int qo = (L >> 4) * 2;   // float4 index of this lane's 8-elem k-slice

  f32x4 gH, gX;
#pragma unroll
  for (int r = 0; r < 4; ++r) { gH[r] = 0.f; gX[r] = 0.f; }

#pragma unroll
  for (int c = 0; c < 16; ++c) {
    const float4 f0 = nb4[qo + c * 8];
    const float4 f1 = nb4[qo + 1 + c * 8];
    const float4 e0 = ei4[qo + c * 8];
    const float4 e1 = ei4[qo + 1 + c * 8];
    float v[8];
    v[0] = f0.x - e0.x; v[1] = f0.y - e0.y; v[2] = f0.z - e0.z; v[3] = f0.w - e0.w;
    v[4] = f1.x - e1.x; v[5] = f1.y - e1.y; v[6] = f1.z - e1.z; v[7] = f1.w - e1.w;
    short8 ah, al;
#pragma unroll
    for (int q = 0; q < 8; ++q) {
      short hh, ll;
      bf16split(v[q], hh, ll);
      ah[q] = hh; al[q] = ll;
    }
    gH = __builtin_amdgcn_mfma_f32_16x16x32_bf16(ah, ah, gH, 0, 0, 0);
    gX = __builtin_amdgcn_mfma_f32_16x16x32_bf16(ah, al, gX, 0, 0, 0);
    gX = __builtin_amdgcn_mfma_f32_16x16x32_bf16(al, ah, gX, 0, 0, 0);
  }

  // write gram to per-wave LDS: C/D layout col=L&15, row=(L>>4)*4+q
#pragma unroll
  for (int q = 0; q < 4; ++q)
    gsm[wid][((L >> 4) * 4 + q) * 17 + (L & 15)] = gH[q] + gX[q];
  asm volatile("s_waitcnt lgkmcnt(0)" ::: "memory");

  if (L < 16) {
    const float dv = gsm[wid][L * 17 + L];
    const float nrm = sqrtf(fmaxf(dv, 0.f));
    gsm[wid][272 + L] = 1.0f / fmaxf(nrm, 1e-8f);
  }
  asm volatile("s_waitcnt lgkmcnt(0)" ::: "memory");

  // cosines for pairs p = L and p+64
  float c0 = CINF, c1 = CINF;
#pragma unroll
  for (int s = 0; s < 2; ++s) {
    const int p = L + 64 * s;
    if (p < NPAIR) {
      int a = 0, rem = p, cnt = 14;
      while (rem >= cnt) { rem -= cnt; --cnt; ++a; }
      const int b = a + 1 + rem;
      const float cv = gsm[wid][a * 17 + b] * gsm[wid][272 + a] * gsm[wid][272 + b];
      if (s == 0) c0 = cv; else c1 = cv;
    }
  }

  // shuffle bitonic sort of 128 elems (2 per lane), ascending
#pragma unroll
  for (int k = 2; k <= 128; k <<= 1) {
#pragma unroll
    for (int j = k >> 1; j >= 1; j >>= 1) {
      const bool dir = ((L & (k >> 1)) == 0);
      if (j == 1) {
        const float lo = fminf(c0, c1), hi = fmaxf(c0, c1);
        c0 = dir ? lo : hi;
        c1 = dir ? hi : lo;
      } else {
        const int m = j >> 1;
        const float o0 = __shfl_xor(c0, m, 64);
        const float o1 = __shfl_xor(c1, m, 64);
        const bool lower = ((L & m) == 0);
        c0 = (lower == dir) ? fminf(c0, o0) : fmaxf(c0, o0);
        c1 = (lower == dir) ? fminf(c1, o1) : fmaxf(c1, o1);
      }
    }
  }

  // angular loss vs sorted reference (rank 2L, 2L+1)
  float part = 0.f;
  {
    const int r0 = 2 * L, r1 = 2 * L + 1;
    if (r0 < NPAIR) { const float dd = c0 - refa[(size_t)i * NPAIR + r0]; part += dd * dd; }
    if (r1 < NPAIR) { const float dd = c1 - refa[(size_t)i * NPAIR + r1]; part += dd * dd; }
  }
  part = wave_sum_f(part);
  if (L == 0) {
    atomicAdd(&acc[0], (double)curvs);
    atomicAdd(&acc[1], (double)part);
  }
}

// ---------------------------------------------------------------- fin
__global__ void fin_kernel(const double* __restrict__ acc,
                           float* __restrict__ out) {
  if (threadIdx.x == 0 && blockIdx.x == 0) {
    const double curv = acc[0] / ((double)NPTS * (double)KNNK);
    const double ang  = acc[1] / ((double)NPTS * (double)NPAIR);
    out[0] = (float)(0.3 * curv + 0.7 * ang);
  }
}

// ---------------------------------------------------------------- launch
extern "C" void kernel_launch(void* const* d_in, const int* in_sizes, int n_in,
                              void* d_out, int out_size, void* d_ws,
                              size_t ws_size, hipStream_t stream) {
  const float* E    = (const float*)d_in[0];
  const float* refc = (const float*)d_in[1];
  const float* refa = (const float*)d_in[2];
  float* out = (float*)d_out;

  char* ws = (char*)d_ws;
  double* acc = (double*)ws;
  float*  sqn = (float*)(ws + 1024);
  ushort* Ehi = (ushort*)(ws + 1048576);
  ushort* Elo = (ushort*)(ws + 9437184);
  float*  cd  = (float*)(ws + 17825792);
  int*    ci  = (int*)(ws + 21757952);

  prep_kernel<<<NPTS / 4, 256, 0, stream>>>(E, sqn, Ehi, Elo, acc);
  knn_kernel<<<dim3(NPTS / NI, NJSPLIT), 256, 0, stream>>>(Ehi, Elo, sqn, cd, ci);
  sig_kernel<<<NPTS / 4, 256, 0, stream>>>(E, cd, ci, refc, refa, acc);
  fin_kernel<<<1, 64, 0, stream>>>(acc, out);
}

// Round 7
// 403.401 us; speedup vs baseline: 1.6424x; 1.4184x over previous
//
#include <hip/hip_runtime.h>
#include <hip/hip_bf16.h>
#include <math.h>

#define NPTS  8192
#define DIM   512
#define KNNK  15
#define NPAIR 105
#define CINF  3.0e38f

// knn tiling
#define NI      128
#define NJSPLIT 8
#define NJ      (NPTS/NJSPLIT)   // 1024
#define JS      128
#define NSUB    (NJ/JS)          // 8
#define BK      32
#define NCH     (DIM/BK)         // 16
#define DSTRIDE 132              // 16B-aligned rows; writes conflict-free, b128 scan reads 2-way (free)

// knn LDS byte map: sdist[128][132] aliases the two 32KB staging buffers
#define BUF0_OFF   0
#define BUF1_OFF   33792
#define EXI_OFF    67584
#define SQJ_OFF    68096
#define TLS_OFF    72192
#define KNN_LDS    73216

typedef __attribute__((ext_vector_type(8))) short short8;
typedef __attribute__((ext_vector_type(4))) float f32x4;

static __device__ __forceinline__ float wave_sum_f(float v) {
#pragma unroll
  for (int m = 32; m > 0; m >>= 1) v += __shfl_xor(v, m, 64);
  return v;
}

static __device__ __forceinline__ void load_lds16(const void* g, void* l) {
  __builtin_amdgcn_global_load_lds(
      (const __attribute__((address_space(1))) void*)g,
      (__attribute__((address_space(3))) void*)l, 16, 0, 0);
}

static __device__ __forceinline__ void bf16split(float x, short& h, short& l) {
  __hip_bfloat16 hb = __float2bfloat16(x);
  const float hf = __bfloat162float(hb);
  __hip_bfloat16 lb = __float2bfloat16(x - hf);
  h = *(short*)&hb;
  l = *(short*)&lb;
}

// ---------------------------------------------------------------- prep
__global__ __launch_bounds__(256) void prep_kernel(
    const float* __restrict__ E, float* __restrict__ sqn,
    ushort* __restrict__ Ehi, ushort* __restrict__ Elo) {
  const int row  = blockIdx.x * 4 + (threadIdx.x >> 6);
  const int lane = threadIdx.x & 63;
  float s = 0.f;
#pragma unroll
  for (int c = 0; c < 8; ++c) {
    const int d0 = lane + 64 * c;
    const float x = E[(size_t)row * DIM + d0];
    s = fmaf(x, x, s);
    short h, l;
    bf16split(x, h, l);
    Ehi[(size_t)row * DIM + d0] = (ushort)h;
    Elo[(size_t)row * DIM + d0] = (ushort)l;
  }
  s = wave_sum_f(s);
  if (lane == 0) sqn[row] = s;
}

// ---------------------------------------------------------------- knn
// grid (64, 8): blockIdx.x = i-tile -> XCD = x%8 (A-set L2-resident).
// K-loop: BK=32, 16x16x32 MFMA, double-buffered global_load_lds.
// Scan: contiguous 64-col half-row per thread, float4 batches with
// min-of-4 guard pre-check.
__global__ __launch_bounds__(256, 2) void knn_kernel(
    const ushort* __restrict__ Ehi, const ushort* __restrict__ Elo,
    const float* __restrict__ sqn,
    float* __restrict__ cd, int* __restrict__ ci) {
  __shared__ __align__(16) char sm[KNN_LDS];
  float* sdist = (float*)sm;
  float* exi   = (float*)(sm + EXI_OFF);
  float* sqjs  = (float*)(sm + SQJ_OFF);
  float* tls   = (float*)(sm + TLS_OFF);

  const int tid = threadIdx.x;
  const int w   = tid >> 6;
  const int L   = tid & 63;
  const int wr  = w >> 1;
  const int wc  = w & 1;
  const int i0  = blockIdx.x * NI;     // i-tile (XCD-affine)
  const int jsplit = blockIdx.y;
  const int j0  = jsplit * NJ;

  if (tid < 32) ((float4*)exi)[tid] = ((const float4*)(sqn + i0))[tid];
  ((float4*)sqjs)[tid] = ((const float4*)(sqn + j0))[tid];
  tls[tid] = CINF;

  const ushort* srcBase = (w & 1) ? Elo : Ehi;   // tiles: 0=Ahi 1=Alo 2=Bhi 3=Blo
  const int lrow = L >> 2;
  const int lk8  = (L & 3) * 8;

  const int myrow = tid >> 1;
  const int h     = tid & 1;
  const int gi    = i0 + myrow;

  float td[15]; int tj[15];
#pragma unroll
  for (int p = 0; p < 15; ++p) { td[p] = CINF; tj[p] = -1; }

  __syncthreads();

  for (int js = 0; js < NSUB; ++js) {
    const int jrow0 = j0 + js * JS;
    const int trow0 = (w < 2) ? i0 : jrow0;
    const ushort* gbase = srcBase + (size_t)(trow0 + lrow) * DIM + lk8;

    f32x4 acc[4][4];
#pragma unroll
    for (int fr = 0; fr < 4; ++fr)
#pragma unroll
      for (int fc = 0; fc < 4; ++fc)
#pragma unroll
        for (int r = 0; r < 4; ++r) acc[fr][fc][r] = 0.f;

    // prologue: stage chunk 0 into buf0
    {
      char* lp = sm + BUF0_OFF + w * 8192;
#pragma unroll
      for (int s = 0; s < 8; ++s)
        load_lds16(gbase + (size_t)s * 16 * DIM, lp + s * 1024);
    }
    __syncthreads();

#pragma unroll 2
    for (int ch = 0; ch < NCH; ++ch) {
      const int cb = (ch & 1) ? BUF1_OFF : BUF0_OFF;
      const int nbo = (ch & 1) ? BUF0_OFF : BUF1_OFF;
      if (ch < NCH - 1) {
        char* lp = sm + nbo + w * 8192;
        const ushort* gp = gbase + (ch + 1) * BK;
#pragma unroll
        for (int s = 0; s < 8; ++s)
          load_lds16(gp + (size_t)s * 16 * DIM, lp + s * 1024);
      }

      const ushort* sAhi = (const ushort*)(sm + cb);
      const ushort* sAlo = (const ushort*)(sm + cb + 8192);
      const ushort* sBhi = (const ushort*)(sm + cb + 16384);
      const ushort* sBlo = (const ushort*)(sm + cb + 24576);

      short8 ah[4], al[4], bh[4], bl[4];
      const int q16 = (L >> 4) * 8;
#pragma unroll
      for (int f = 0; f < 4; ++f) {
        const int ra = f * 16 + (L & 15);
        ah[f] = *(const short8*)&sAhi[(wr * 64 + ra) * BK + q16];
        al[f] = *(const short8*)&sAlo[(wr * 64 + ra) * BK + q16];
        bh[f] = *(const short8*)&sBhi[(wc * 64 + ra) * BK + q16];
        bl[f] = *(const short8*)&sBlo[(wc * 64 + ra) * BK + q16];
      }
#pragma unroll
      for (int fr = 0; fr < 4; ++fr)
#pragma unroll
        for (int fc = 0; fc < 4; ++fc) {
          acc[fr][fc] = __builtin_amdgcn_mfma_f32_16x16x32_bf16(ah[fr], bh[fc], acc[fr][fc], 0, 0, 0);
          acc[fr][fc] = __builtin_amdgcn_mfma_f32_16x16x32_bf16(ah[fr], bl[fc], acc[fr][fc], 0, 0, 0);
          acc[fr][fc] = __builtin_amdgcn_mfma_f32_16x16x32_bf16(al[fr], bh[fc], acc[fr][fc], 0, 0, 0);
        }
      __syncthreads();   // drains next-chunk staging; orders buffer reuse
    }

    // ---- partial distances (sqj - 2*dot; exi added at merge)
    float sqjv[4];
#pragma unroll
    for (int fc = 0; fc < 4; ++fc)
      sqjv[fc] = sqjs[js * 128 + wc * 64 + fc * 16 + (L & 15)];
#pragma unroll
    for (int fr = 0; fr < 4; ++fr)
#pragma unroll
      for (int fc = 0; fc < 4; ++fc)
#pragma unroll
        for (int r = 0; r < 4; ++r) {
          const int row_l = wr * 64 + fr * 16 + (L >> 4) * 4 + r;
          const int col_l = wc * 64 + fc * 16 + (L & 15);
          sdist[row_l * DSTRIDE + col_l] = sqjv[fc] - 2.0f * acc[fr][fc][r];
        }
    __syncthreads();

    // ---- tau + self-poke + batch-4 scan over contiguous half-row
    const float tau = fminf(tls[myrow * 2], tls[myrow * 2 + 1]);
    const int selfc = gi - jrow0;
    if (selfc >= 0 && selfc < JS && h == (selfc >> 6))
      sdist[myrow * DSTRIDE + selfc] = CINF;

    const float* rp = sdist + myrow * DSTRIDE + 64 * h;
    float guard = fminf(tau, td[14]);
    const int jb = jrow0 + 64 * h;
#pragma unroll 2
    for (int q = 0; q < 16; ++q) {
      const float4 dv = *(const float4*)&rp[4 * q];
      const float mn = fminf(fminf(dv.x, dv.y), fminf(dv.z, dv.w));
      if (mn < guard) {
        const float c4[4] = {dv.x, dv.y, dv.z, dv.w};
#pragma unroll
        for (int t = 0; t < 4; ++t) {
          const float dd = c4[t];
          if (dd < guard) {
            float cdv = dd; int cjv = jb + 4 * q + t;
#pragma unroll
            for (int p = 0; p < 15; ++p) {
              const bool lt = cdv < td[p];
              const float vmin = lt ? cdv : td[p];
              const float vmax = lt ? td[p] : cdv;
              const int imin = lt ? cjv : tj[p];
              const int imax = lt ? tj[p] : cjv;
              td[p] = vmin; tj[p] = imin; cdv = vmax; cjv = imax;
            }
            guard = fminf(tau, td[14]);
          }
        }
      }
    }
    tls[myrow * 2 + h] = td[14];
    __syncthreads();
  }

  // ---- pair-merge -> top-15 per (row, split); restore +exi, clamp
  float* md  = sdist;
  int*   mi_ = (int*)(sm + 16384);
#pragma unroll
  for (int p = 0; p < 15; ++p) {
    md[(myrow * 2 + h) * 15 + p]  = td[p];
    mi_[(myrow * 2 + h) * 15 + p] = tj[p];
  }
  __syncthreads();
  if (h == 0) {
    const float* da = &md[(myrow * 2 + 0) * 15];
    const float* db = &md[(myrow * 2 + 1) * 15];
    const int*   ia = &mi_[(myrow * 2 + 0) * 15];
    const int*   ib = &mi_[(myrow * 2 + 1) * 15];
    const float exr = exi[myrow];
    int pa = 0, pb = 0;
    const size_t base = ((size_t)gi * NJSPLIT + jsplit) * KNNK;
    for (int s2 = 0; s2 < KNNK; ++s2) {
      const float va = da[pa], vb = db[pb];
      float v; int ix;
      if (va <= vb) { v = va; ix = ia[pa]; ++pa; }
      else          { v = vb; ix = ib[pb]; ++pb; }
      cd[base + s2] = fmaxf(v + exr, 0.f);
      ci[base + s2] = ix;
    }
  }
}

// ---------------------------------------------------------------- sig
// One wave per point. Fused: 8-way candidate merge -> curvature ->
// raw-difference gram via split-bf16 MFMA (norms from the diagonal) ->
// shuffle bitonic-128 -> per-wave partial to global (NO atomics).
__global__ __launch_bounds__(256) void sig_kernel(
    const float* __restrict__ E, const float* __restrict__ cd,
    const int* __restrict__ ci, const float* __restrict__ refc,
    const float* __restrict__ refa, float2* __restrict__ pacc) {
  __shared__ float gsm[4][292];   // per-wave: gram 16x17 (=272) + inv[16]

  const int tid = threadIdx.x;
  const int wid = tid >> 6;
  const int L   = tid & 63;
  const int i   = blockIdx.x * 4 + wid;

  // ---- merge 8 sorted 15-lists -> top-15 (d, nb); lane-group captures row L&15
  const size_t mbase = (size_t)i * (NJSPLIT * KNNK);
  float v0 = (L < 120)      ? cd[mbase + L]      : CINF;
  float v1 = (L + 64 < 120) ? cd[mbase + L + 64] : CINF;
  int   j0v = (L < 120)      ? ci[mbase + L]      : -1;
  int   j1v = (L + 64 < 120) ? ci[mbase + L + 64] : -1;
  float myd = 0.f; int mynb = i;
  for (int sel = 0; sel < KNNK; ++sel) {
    float v; int idx, slot;
    if (v1 < v0) { v = v1; idx = j1v; slot = (L << 1) | 1; }
    else         { v = v0; idx = j0v; slot = (L << 1); }
#pragma unroll
    for (int off = 32; off > 0; off >>= 1) {
      const float ov = __shfl_down(v, off, 64);
      const int   oi = __shfl_down(idx, off, 64);
      const int   os = __shfl_down(slot, off, 64);
      if (ov < v) { v = ov; idx = oi; slot = os; }
    }
    const float vmin = __shfl(v, 0, 64);
    const int   imin = __shfl(idx, 0, 64);
    const int   smin = __shfl(slot, 0, 64);
    if ((L & 15) == sel) { myd = sqrtf(fmaxf(vmin, 1e-12f)); mynb = imin; }
    if (L == (smin >> 1)) { if (smin & 1) v1 = CINF; else v0 = CINF; }
  }

  // ---- curvature (lanes 0..14 hold d_0..d_14)
  float curvs;
  {
    float dd = (L < KNNK) ? myd : 0.f;
    float tot = wave_sum_f(dd);
    float mean_d = tot / (float)KNNK + 1e-8f;
    float diff = (L < KNNK) ? (dd / mean_d - refc[i * KNNK + L]) : 0.f;
    curvs = wave_sum_f(diff * diff);
  }

  // ---- gram of raw neighbor differences (row = L&15; row 15 = self -> zero)
  const float4* nb4 = (const float4*)(E + (size_t)mynb * DIM);
  const float4* ei4 = (const float4*)(E + (size_t)i * DIM);
  const int qo = (L >> 4) * 2;   // float4 index of this lane's 8-elem k-slice

  f32x4 gH, gX;
#pragma unroll
  for (int r = 0; r < 4; ++r) { gH[r] = 0.f; gX[r] = 0.f; }

#pragma unroll
  for (int c = 0; c < 16; ++c) {
    const float4 f0 = nb4[qo + c * 8];
    const float4 f1 = nb4[qo + 1 + c * 8];
    const float4 e0 = ei4[qo + c * 8];
    const float4 e1 = ei4[qo + 1 + c * 8];
    float v[8];
    v[0] = f0.x - e0.x; v[1] = f0.y - e0.y; v[2] = f0.z - e0.z; v[3] = f0.w - e0.w;
    v[4] = f1.x - e1.x; v[5] = f1.y - e1.y; v[6] = f1.z - e1.z; v[7] = f1.w - e1.w;
    short8 ah, al;
#pragma unroll
    for (int q = 0; q < 8; ++q) {
      short hh, ll;
      bf16split(v[q], hh, ll);
      ah[q] = hh; al[q] = ll;
    }
    gH = __builtin_amdgcn_mfma_f32_16x16x32_bf16(ah, ah, gH, 0, 0, 0);
    gX = __builtin_amdgcn_mfma_f32_16x16x32_bf16(ah, al, gX, 0, 0, 0);
    gX = __builtin_amdgcn_mfma_f32_16x16x32_bf16(al, ah, gX, 0, 0, 0);
  }

  // write gram to per-wave LDS: C/D layout col=L&15, row=(L>>4)*4+q
#pragma unroll
  for (int q = 0; q < 4; ++q)
    gsm[wid][((L >> 4) * 4 + q) * 17 + (L & 15)] = gH[q] + gX[q];
  asm volatile("s_waitcnt lgkmcnt(0)" ::: "memory");

  if (L < 16) {
    const float dv = gsm[wid][L * 17 + L];
    const float nrm = sqrtf(fmaxf(dv, 0.f));
    gsm[wid][272 + L] = 1.0f / fmaxf(nrm, 1e-8f);
  }
  asm volatile("s_waitcnt lgkmcnt(0)" ::: "memory");

  // cosines for pairs p = L and p+64
  float c0 = CINF, c1 = CINF;
#pragma unroll
  for (int s = 0; s < 2; ++s) {
    const int p = L + 64 * s;
    if (p < NPAIR) {
      int a = 0, rem = p, cnt = 14;
      while (rem >= cnt) { rem -= cnt; --cnt; ++a; }
      const int b = a + 1 + rem;
      const float cv = gsm[wid][a * 17 + b] * gsm[wid][272 + a] * gsm[wid][272 + b];
      if (s == 0) c0 = cv; else c1 = cv;
    }
  }

  // shuffle bitonic sort of 128 elems (2 per lane), ascending
#pragma unroll
  for (int k = 2; k <= 128; k <<= 1) {
#pragma unroll
    for (int j = k >> 1; j >= 1; j >>= 1) {
      const bool dir = ((L & (k >> 1)) == 0);
      if (j == 1) {
        const float lo = fminf(c0, c1), hi = fmaxf(c0, c1);
        c0 = dir ? lo : hi;
        c1 = dir ? hi : lo;
      } else {
        const int m = j >> 1;
        const float o0 = __shfl_xor(c0, m, 64);
        const float o1 = __shfl_xor(c1, m, 64);
        const bool lower = ((L & m) == 0);
        c0 = (lower == dir) ? fminf(c0, o0) : fmaxf(c0, o0);
        c1 = (lower == dir) ? fminf(c1, o1) : fmaxf(c1, o1);
      }
    }
  }

  // angular loss vs sorted reference (rank 2L, 2L+1)
  float part = 0.f;
  {
    const int r0 = 2 * L, r1 = 2 * L + 1;
    if (r0 < NPAIR) { const float dd = c0 - refa[(size_t)i * NPAIR + r0]; part += dd * dd; }
    if (r1 < NPAIR) { const float dd = c1 - refa[(size_t)i * NPAIR + r1]; part += dd * dd; }
  }
  part = wave_sum_f(part);
  if (L == 0) pacc[i] = make_float2(curvs, part);   // non-atomic per-wave slot
}

// ---------------------------------------------------------------- fin
// Reduce 8192 per-point partials in doubles; single block.
__global__ __launch_bounds__(256) void fin_kernel(
    const float2* __restrict__ pacc, float* __restrict__ out) {
  __shared__ double redc[4], reda[4];
  const int tid = threadIdx.x;
  const int wid = tid >> 6;
  const int L   = tid & 63;
  double sc = 0.0, sa = 0.0;
#pragma unroll
  for (int q = 0; q < 32; ++q) {
    const float2 p = pacc[tid + 256 * q];
    sc += (double)p.x;
    sa += (double)p.y;
  }
#pragma unroll
  for (int m = 32; m > 0; m >>= 1) {
    sc += __shfl_xor(sc, m, 64);
    sa += __shfl_xor(sa, m, 64);
  }
  if (L == 0) { redc[wid] = sc; reda[wid] = sa; }
  __syncthreads();
  if (tid == 0) {
    const double curv = (redc[0] + redc[1] + redc[2] + redc[3]) /
                        ((double)NPTS * (double)KNNK);
    const double ang  = (reda[0] + reda[1] + reda[2] + reda[3]) /
                        ((double)NPTS * (double)NPAIR);
    out[0] = (float)(0.3 * curv + 0.7 * ang);
  }
}

// ---------------------------------------------------------------- launch
extern "C" void kernel_launch(void* const* d_in, const int* in_sizes, int n_in,
                              void* d_out, int out_size, void* d_ws,
                              size_t ws_size, hipStream_t stream) {
  const float* E    = (const float*)d_in[0];
  const float* refc = (const float*)d_in[1];
  const float* refa = (const float*)d_in[2];
  float* out = (float*)d_out;

  char* ws = (char*)d_ws;
  float*  sqn  = (float*)(ws + 1024);
  float2* pacc = (float2*)(ws + 65536);      // 64 KB of per-wave partials
  ushort* Ehi  = (ushort*)(ws + 1048576);
  ushort* Elo  = (ushort*)(ws + 9437184);
  float*  cd   = (float*)(ws + 17825792);
  int*    ci   = (int*)(ws + 21757952);

  prep_kernel<<<NPTS / 4, 256, 0, stream>>>(E, sqn, Ehi, Elo);
  knn_kernel<<<dim3(NPTS / NI, NJSPLIT), 256, 0, stream>>>(Ehi, Elo, sqn, cd, ci);
  sig_kernel<<<NPTS / 4, 256, 0, stream>>>(E, cd, ci, refc, refa, pacc);
  fin_kernel<<<1, 256, 0, stream>>>(pacc, out);
}